// Round 1
// 373.121 us; speedup vs baseline: 1.1547x; 1.1547x over previous
//
#include <hip/hip_runtime.h>
#include <math.h>

// Sinkhorn [B=32, N=1024, N=1024] fp32, TAU=1, 10 iters.
// Identity: log_s == s + r[b,i] + c[b,j] always.
//   r = -LSE_j(s + c),  c = -LSE_i(s + r),  out = exp(s + r + c).
// v2: fused kernel reads its 32-row stripe of s ONCE; each thread keeps its
// 4x16 elements in registers across phase A (row LSE) and phase B (column
// partials with the fresh r). Cross-wave column merge goes through LDS.

#define BATCH 32
#define N 1024
#define RCHUNKS 32
#define ROWS_PER_BLK 32        // N / RCHUNKS
#define PCHUNKS RCHUNKS        // column partials per batch

// Grid = BATCH*RCHUNKS = 1024, block = 512 (8 waves, wave handles 4 rows).
// LDS 64 KB + ~110 VGPR -> 2 blocks/CU (16 waves/CU).
__global__ __launch_bounds__(512, 4) void fused_pair_kernel(
    const float* __restrict__ s, const float* __restrict__ c,
    float* __restrict__ r, float* __restrict__ pm, float* __restrict__ pl,
    int has_c)
{
    const int bc    = blockIdx.x;          // b * RCHUNKS + chunk
    const int b     = bc >> 5;
    const int chunk = bc & 31;
    const int row0  = chunk * ROWS_PER_BLK;
    const int wave  = threadIdx.x >> 6;
    const int lane  = threadIdx.x & 63;

    __shared__ float4 sm4[8][256];         // per-wave column max partials
    __shared__ float4 sl4[8][256];         // per-wave column sum partials

    // c fragment for this lane's 16 columns (columns identical for all 4 rows).
    // Read direct from global: 4 KB per batch, L2-broadcast across waves.
    float4 cv[4];
    if (has_c) {
        const float4* c4 = (const float4*)(c + b * N);
#pragma unroll
        for (int k = 0; k < 4; k++) cv[k] = c4[lane + 64 * k];
    } else {
#pragma unroll
        for (int k = 0; k < 4; k++) cv[k] = make_float4(0.f, 0.f, 0.f, 0.f);
    }

    // Phase A0: stream all 16 float4 loads (independent -> deep MLP),
    // retain x = s + c in registers. Statically indexed => stays in VGPRs.
    float x[4][16];
#pragma unroll
    for (int rp = 0; rp < 4; rp++) {
        const float4* srow =
            (const float4*)(s + ((size_t)(b * N + row0 + wave * 4 + rp)) * N);
#pragma unroll
        for (int k = 0; k < 4; k++) {
            float4 v = srow[lane + 64 * k];
            x[rp][4*k+0] = v.x + cv[k].x;
            x[rp][4*k+1] = v.y + cv[k].y;
            x[rp][4*k+2] = v.z + cv[k].z;
            x[rp][4*k+3] = v.w + cv[k].w;
        }
    }

    // Phase A1: row LSE per rp. Butterfly reduce leaves result in ALL lanes,
    // so rv needs no LDS broadcast.
    float rv[4];
#pragma unroll
    for (int rp = 0; rp < 4; rp++) {
        float m = fmaxf(
            fmaxf(fmaxf(fmaxf(x[rp][0],  x[rp][1]),  fmaxf(x[rp][2],  x[rp][3])),
                  fmaxf(fmaxf(x[rp][4],  x[rp][5]),  fmaxf(x[rp][6],  x[rp][7]))),
            fmaxf(fmaxf(fmaxf(x[rp][8],  x[rp][9]),  fmaxf(x[rp][10], x[rp][11])),
                  fmaxf(fmaxf(x[rp][12], x[rp][13]), fmaxf(x[rp][14], x[rp][15]))));
#pragma unroll
        for (int off = 32; off > 0; off >>= 1) m = fmaxf(m, __shfl_xor(m, off, 64));
        float s0 = 0.f, s1 = 0.f, s2 = 0.f, s3 = 0.f;
#pragma unroll
        for (int t = 0; t < 4; t++) {
            s0 += __expf(x[rp][t]      - m);
            s1 += __expf(x[rp][4 + t]  - m);
            s2 += __expf(x[rp][8 + t]  - m);
            s3 += __expf(x[rp][12 + t] - m);
        }
        float sum = (s0 + s1) + (s2 + s3);
#pragma unroll
        for (int off = 32; off > 0; off >>= 1) sum += __shfl_xor(sum, off, 64);
        rv[rp] = -(m + __logf(sum));
        if (lane == 0) r[b * N + row0 + wave * 4 + rp] = rv[rp];
    }

    // Phase B: per-column partial over this wave's 4 rows, entirely from
    // registers (no global re-read). float4 LDS writes: conflict-free.
#pragma unroll
    for (int k = 0; k < 4; k++) {
        float pmv[4], plv[4];
#pragma unroll
        for (int e = 0; e < 4; e++) {
            float x0 = x[0][4*k+e] + rv[0];
            float x1 = x[1][4*k+e] + rv[1];
            float x2 = x[2][4*k+e] + rv[2];
            float x3 = x[3][4*k+e] + rv[3];
            float m = fmaxf(fmaxf(x0, x1), fmaxf(x2, x3));
            plv[e] = __expf(x0 - m) + __expf(x1 - m) +
                     __expf(x2 - m) + __expf(x3 - m);
            pmv[e] = m;
        }
        sm4[wave][lane + 64 * k] = make_float4(pmv[0], pmv[1], pmv[2], pmv[3]);
        sl4[wave][lane + 64 * k] = make_float4(plv[0], plv[1], plv[2], plv[3]);
    }
    __syncthreads();

    // Merge the 8 waves' partials per column (stride-1 reads, conflict-free),
    // write one partial per column for this chunk.
    const float* smf = (const float*)sm4;
    const float* slf = (const float*)sl4;
#pragma unroll
    for (int cc = 0; cc < 2; cc++) {
        const int col = threadIdx.x + cc * 512;
        float M = smf[col], L = slf[col];
#pragma unroll
        for (int w = 1; w < 8; w++) {
            float m = smf[w * N + col], l = slf[w * N + col];
            float mn = fmaxf(M, m);
            L = L * __expf(M - mn) + l * __expf(m - mn);
            M = mn;
        }
        pm[(size_t)bc * N + col] = M;
        pl[(size_t)bc * N + col] = L;
    }
}

// Combine 32 chunk-partials per column -> c. Grid = BATCH*4, block = 1024.
__global__ __launch_bounds__(1024) void col_combine_kernel(
    const float* __restrict__ pm, const float* __restrict__ pl,
    float* __restrict__ c)
{
    const int b  = blockIdx.x >> 2;
    const int q  = blockIdx.x & 3;
    const int jc = threadIdx.x & 255;
    const int kg = threadIdx.x >> 8;      // 0..3, 8 chunks each
    const int j  = q * 256 + jc;
    float M = -3.0e38f, L = 0.f;
#pragma unroll
    for (int k = 0; k < 8; k++) {
        const int kk = kg * 8 + k;
        float m = pm[((size_t)(b * PCHUNKS + kk)) * N + j];
        float l = pl[((size_t)(b * PCHUNKS + kk)) * N + j];
        float mn = fmaxf(M, m);
        L = L * __expf(M - mn) + l * __expf(m - mn); M = mn;
    }
    __shared__ float smm[4][256], sll[4][256];
    smm[kg][jc] = M; sll[kg][jc] = L;
    __syncthreads();
    if (kg == 0) {
#pragma unroll
        for (int g2 = 1; g2 < 4; g2++) {
            float m = smm[g2][jc], l = sll[g2][jc];
            float mn = fmaxf(M, m);
            L = L * __expf(M - mn) + l * __expf(m - mn); M = mn;
        }
        c[b * N + j] = -(M + __logf(L));
    }
}

// ---- fallback path (tiny workspace): round-1 style kernels ----
__global__ __launch_bounds__(256) void zero_c_kernel(float* __restrict__ c) {
    c[blockIdx.x * 256 + threadIdx.x] = 0.0f;
}

__global__ __launch_bounds__(256) void row_lse_kernel(const float* __restrict__ s,
                                                      const float* __restrict__ c,
                                                      float* __restrict__ r) {
    const int wave = threadIdx.x >> 6;
    const int lane = threadIdx.x & 63;
    const int row  = blockIdx.x * 4 + wave;
    const int b    = row >> 10;
    const float4* srow = (const float4*)(s + (size_t)row * N);
    const float4* crow = (const float4*)(c + (size_t)b * N);
    float x[16];
#pragma unroll
    for (int k = 0; k < 4; k++) {
        float4 v = srow[lane + k * 64];
        float4 cv = crow[lane + k * 64];
        x[4*k+0]=v.x+cv.x; x[4*k+1]=v.y+cv.y; x[4*k+2]=v.z+cv.z; x[4*k+3]=v.w+cv.w;
    }
    float m = x[0];
#pragma unroll
    for (int t = 1; t < 16; t++) m = fmaxf(m, x[t]);
#pragma unroll
    for (int off = 32; off > 0; off >>= 1) m = fmaxf(m, __shfl_xor(m, off, 64));
    float sum = 0.f;
#pragma unroll
    for (int t = 0; t < 16; t++) sum += __expf(x[t] - m);
#pragma unroll
    for (int off = 32; off > 0; off >>= 1) sum += __shfl_xor(sum, off, 64);
    if (lane == 0) r[row] = -(m + __logf(sum));
}

__global__ __launch_bounds__(1024) void col_lse_direct_kernel(const float* __restrict__ s,
                                                              const float* __restrict__ r,
                                                              float* __restrict__ c) {
    const int b = blockIdx.x;
    const int j = threadIdx.x;
    const float* rb = r + b * N;
    const float* base = s + (size_t)b * N * N + j;
    float m = -3.0e38f, l = 0.f;
    for (int i = 0; i < N; i++) {
        float x  = base[(size_t)i * N] + rb[i];
        float mn = fmaxf(m, x);
        l = l * __expf(m - mn) + __expf(x - mn);
        m = mn;
    }
    c[b * N + j] = -(m + __logf(l));
}
// ---- end fallback ----

__global__ __launch_bounds__(256) void finalize_kernel(const float* __restrict__ s,
                                                       const float* __restrict__ r,
                                                       const float* __restrict__ c,
                                                       float* __restrict__ out) {
    const int f4  = blockIdx.x * 256 + threadIdx.x;
    const int j4  = f4 & 255;
    const int row = f4 >> 8;
    const int b   = row >> 10;
    float4 v  = ((const float4*)s)[f4];
    float  rr = r[row];
    float4 cc = ((const float4*)c)[(b << 8) + j4];
    float4 o;
    o.x = __expf(v.x + rr + cc.x);
    o.y = __expf(v.y + rr + cc.y);
    o.z = __expf(v.z + rr + cc.z);
    o.w = __expf(v.w + rr + cc.w);
    ((float4*)out)[f4] = o;
}

extern "C" void kernel_launch(void* const* d_in, const int* in_sizes, int n_in,
                              void* d_out, int out_size, void* d_ws, size_t ws_size,
                              hipStream_t stream) {
    const float* s = (const float*)d_in[0];
    float* out = (float*)d_out;

    float* c  = (float*)d_ws;                       // BATCH*N
    float* r  = c + BATCH * N;                      // BATCH*N
    float* pm = r + BATCH * N;                      // BATCH*PCHUNKS*N
    float* pl = pm + BATCH * PCHUNKS * N;           // BATCH*PCHUNKS*N

    const size_t needed =
        (size_t)(2 * BATCH * N + 2 * BATCH * PCHUNKS * N) * sizeof(float);

    if (ws_size >= needed) {
        for (int p = 0; p < 5; p++) {
            fused_pair_kernel<<<BATCH * RCHUNKS, 512, 0, stream>>>(
                s, c, r, pm, pl, p > 0 ? 1 : 0);
            col_combine_kernel<<<BATCH * 4, 1024, 0, stream>>>(pm, pl, c);
        }
    } else {
        zero_c_kernel<<<(BATCH * N) / 256, 256, 0, stream>>>(c);
        for (int it = 0; it < 10; it++) {
            if ((it & 1) == 0)
                row_lse_kernel<<<(BATCH * N) / 4, 256, 0, stream>>>(s, c, r);
            else
                col_lse_direct_kernel<<<BATCH, 1024, 0, stream>>>(s, r, c);
        }
    }

    const int total_f4 = BATCH * N * N / 4;
    finalize_kernel<<<total_f4 / 256, 256, 0, stream>>>(s, r, c, out);
}